// Round 15
// baseline (371.413 us; speedup 1.0000x reference)
//
#include <hip/hip_runtime.h>

// MLP_48687749268221: out[e] = W3 @ relu(W2 @ relu(W1 @ concat(drug[i0],dis[i1]) + b1) + b2) + b3
// E = 2e6, dims 256 -> 128 -> 64 -> 1. bf16 MFMA, f32 accumulate.
// Round 15: ZERO-BARRIER design. Each wave owns 32 edges end-to-end: L1 B-frags loaded
// DIRECTLY from the bf16 tables (16 B/lane/kt; row read exactly once — same bytes as the
// old gather), all 128 L1 units per wave, private 8 KB H1 region (same-wave lgkmcnt
// ordering, no __syncthreads anywhere). Block = 4 independent waves x 32 edges = 128 edges.

typedef __bf16 bf16x8 __attribute__((ext_vector_type(8)));
typedef unsigned short u16x8 __attribute__((ext_vector_type(8)));
typedef float f32x4 __attribute__((ext_vector_type(4)));

static __device__ __forceinline__ unsigned short f2b(float f) {
  // f32 -> bf16 RTNE (inputs finite)
  unsigned int u = __builtin_bit_cast(unsigned int, f);
  u += 0x7FFFu + ((u >> 16) & 1u);
  return (unsigned short)(u >> 16);
}

static __device__ __forceinline__ f32x4 mfma16(u16x8 a, u16x8 b, f32x4 c) {
  return __builtin_amdgcn_mfma_f32_16x16x32_bf16(
      __builtin_bit_cast(bf16x8, a), __builtin_bit_cast(bf16x8, b), c, 0, 0, 0);
}

// ---------- prologue 1: f32 tables -> bf16 tables ----------
__global__ void cvt_tables(const float* __restrict__ a, const float* __restrict__ b,
                           unsigned short* __restrict__ oa, unsigned short* __restrict__ ob,
                           int na, int nb) {
  const int t = blockIdx.x * blockDim.x + threadIdx.x;
  const int ta = na >> 3;
  const float* src;
  unsigned short* dst;
  int i;
  if (t < ta) {
    src = a; dst = oa; i = t;
  } else {
    i = t - ta;
    if (i >= (nb >> 3)) return;
    src = b; dst = ob;
  }
  const float4 f0 = *(const float4*)(src + i * 8);
  const float4 f1 = *(const float4*)(src + i * 8 + 4);
  u16x8 v;
  v[0] = f2b(f0.x); v[1] = f2b(f0.y); v[2] = f2b(f0.z); v[3] = f2b(f0.w);
  v[4] = f2b(f1.x); v[5] = f2b(f1.y); v[6] = f2b(f1.z); v[7] = f2b(f1.w);
  *(u16x8*)(dst + i * 8) = v;
}

// ---------- prologue 2: weights -> bf16 in A-fragment order (same as R11) ----------
// Frag (16x16x32): lane l holds elem[dim][k], dim = 16*t + (l&15), k = 32*kt + 8*(l>>4) + j.
// W1 slot t = (ut*8 + kt)*64 + l (ut 0..7, kt 0..7); W2: (nt2*4 + kt)*64 + l (nt2 0..3, kt 0..3).
__global__ void cvt_weights(const float* __restrict__ W1, const float* __restrict__ W2,
                            unsigned short* __restrict__ o1, unsigned short* __restrict__ o2) {
  const int t = blockIdx.x * blockDim.x + threadIdx.x;
  if (t < 4096) {
    const int l = t & 63, kt = (t >> 6) & 7, ut = t >> 9;
    const int n = 16 * ut + (l & 15), k0 = 32 * kt + 8 * (l >> 4);
    const float* src = W1 + n * 256 + k0;
    u16x8 v;
#pragma unroll
    for (int j = 0; j < 8; ++j) v[j] = f2b(src[j]);
    *(u16x8*)(o1 + t * 8) = v;
  } else if (t < 5120) {
    const int u = t - 4096;
    const int l = u & 63, kt = (u >> 6) & 3, nt = u >> 8;
    const int n = 16 * nt + (l & 15), k0 = 32 * kt + 8 * (l >> 4);
    const float* src = W2 + n * 128 + k0;
    u16x8 v;
#pragma unroll
    for (int j = 0; j < 8; ++j) v[j] = f2b(src[j]);
    *(u16x8*)(o2 + u * 8) = v;
  }
}

// ---------- main fused kernel ----------
// 256 threads = 4 INDEPENDENT waves; wave wv owns edges [e0 + 32wv, +32) end-to-end.
// No __syncthreads. LDS: per-wave private H1 region, 16 chunks x [32 edges x 16 B] = 8 KB
// (chunk = unit>>3); total 32768 B -> 4 blocks/CU, 16 waves/CU at VGPR <= 128.
__global__ __launch_bounds__(256, 4) void mlp_fused(
    const unsigned short* __restrict__ drugB, const unsigned short* __restrict__ disB,
    const int* __restrict__ eidx, const unsigned short* __restrict__ w1frag,
    const unsigned short* __restrict__ w2frag, const float* __restrict__ b1,
    const float* __restrict__ b2, const float* __restrict__ W3,
    const float* __restrict__ b3, float* __restrict__ out, int E) {
  __shared__ __align__(16) unsigned char smem[32768];

  const int tid = threadIdx.x;
  const int wv = tid >> 6;
  const int l = tid & 63;
  const int l15 = l & 15;
  const int lq = l >> 4;
  const int e0w = blockIdx.x * 128 + wv * 32;
  unsigned char* hb = smem + wv * 8192;  // private H1: 16 x [32 x 16 B]

  // ---- edge indices + row pointers (edge eA = nt0 lane edge, eB = nt1) ----
  int eA = e0w + l15;      if (eA >= E) eA = E - 1;
  int eB = e0w + 16 + l15; if (eB >= E) eB = E - 1;
  const unsigned short* pd0 = drugB + (long)eidx[eA] * 128;
  const unsigned short* pd1 = drugB + (long)eidx[eB] * 128;
  const unsigned short* ps0 = disB + (long)eidx[E + eA] * 128;
  const unsigned short* ps1 = disB + (long)eidx[E + eB] * 128;

  // ---- layer 1: D1[unit][edge]; A = W1 frags (streamed), B = direct global loads ----
  // B-frag (nt,kt): lane l holds edge[16nt+l15] features [32*(kt&3) + 8lq, +8) of the
  // drug row (kt<4) or dis row (kt>=4). Each row byte is read exactly once.
  f32x4 acc1[8][2];
#pragma unroll
  for (int ut = 0; ut < 8; ++ut) {
    acc1[ut][0] = (f32x4){0.f, 0.f, 0.f, 0.f};
    acc1[ut][1] = (f32x4){0.f, 0.f, 0.f, 0.f};
  }
  const unsigned short* w1l = w1frag + l * 8;
#pragma unroll
  for (int kt = 0; kt < 8; ++kt) {
    const int fo = (kt & 3) * 32 + lq * 8;
    const u16x8 b0 = *(const u16x8*)(((kt < 4) ? pd0 : ps0) + fo);
    const u16x8 b1f = *(const u16x8*)(((kt < 4) ? pd1 : ps1) + fo);
#pragma unroll
    for (int ut = 0; ut < 8; ++ut) {
      const u16x8 wf = *(const u16x8*)(w1l + (ut * 8 + kt) * 512);
      acc1[ut][0] = mfma16(wf, b0, acc1[ut][0]);
      acc1[ut][1] = mfma16(wf, b1f, acc1[ut][1]);
    }
  }

  // ---- H1: bias+relu, 4 consecutive units -> ushort4 into private chunked H1 ----
  // lane holds D1[16ut + 4lq + i][16nt + l15]; chunk = 2ut + (lq>>1), slot byte (lq&1)*8.
#pragma unroll
  for (int ut = 0; ut < 8; ++ut) {
    const float4 bv = *(const float4*)(b1 + 16 * ut + 4 * lq);
#pragma unroll
    for (int nt = 0; nt < 2; ++nt) {
      float h0 = acc1[ut][nt][0] + bv.x; h0 = h0 > 0.f ? h0 : 0.f;
      float h1 = acc1[ut][nt][1] + bv.y; h1 = h1 > 0.f ? h1 : 0.f;
      float h2 = acc1[ut][nt][2] + bv.z; h2 = h2 > 0.f ? h2 : 0.f;
      float h3 = acc1[ut][nt][3] + bv.w; h3 = h3 > 0.f ? h3 : 0.f;
      ushort4 hv;
      hv.x = f2b(h0); hv.y = f2b(h1); hv.z = f2b(h2); hv.w = f2b(h3);
      *(ushort4*)(hb + (2 * ut + (lq >> 1)) * 512 + (16 * nt + l15) * 16 + (lq & 1) * 8) = hv;
    }
  }
  // (same-wave ds ordering: compiler inserts lgkmcnt before dependent reads)

  // ---- layer 2: D2[n2][edge]; A = W2 frags (streamed), B = private H1 frags ----
  // B-frag (nt,kt): lane l reads H1 units [32kt + 8lq, +8) of edge 16nt+l15:
  // chunk = 4kt + lq, addr = chunk*512 + e_loc*16.
  f32x4 acc2[4][2];
#pragma unroll
  for (int nt2 = 0; nt2 < 4; ++nt2) {
    acc2[nt2][0] = (f32x4){0.f, 0.f, 0.f, 0.f};
    acc2[nt2][1] = (f32x4){0.f, 0.f, 0.f, 0.f};
  }
  const unsigned short* w2l = w2frag + l * 8;
#pragma unroll
  for (int kt = 0; kt < 4; ++kt) {
    const u16x8 h0 = *(const u16x8*)(hb + (4 * kt + lq) * 512 + l15 * 16);
    const u16x8 h1 = *(const u16x8*)(hb + (4 * kt + lq) * 512 + (16 + l15) * 16);
#pragma unroll
    for (int nt2 = 0; nt2 < 4; ++nt2) {
      const u16x8 wf = *(const u16x8*)(w2l + (nt2 * 4 + kt) * 512);
      acc2[nt2][0] = mfma16(wf, h0, acc2[nt2][0]);
      acc2[nt2][1] = mfma16(wf, h1, acc2[nt2][1]);
    }
  }

  // ---- layer 3: relu(.+b2) dot W3 over all 64 n2 (16/lane), reduce over lq ----
  const float b3v = b3[0];
#pragma unroll
  for (int nt = 0; nt < 2; ++nt) {
    float s = 0.f;
#pragma unroll
    for (int nt2 = 0; nt2 < 4; ++nt2) {
      const float4 b2v = *(const float4*)(b2 + 16 * nt2 + 4 * lq);
      const float4 w3v = *(const float4*)(W3 + 16 * nt2 + 4 * lq);
      float h;
      h = acc2[nt2][nt][0] + b2v.x; s += (h > 0.f ? h : 0.f) * w3v.x;
      h = acc2[nt2][nt][1] + b2v.y; s += (h > 0.f ? h : 0.f) * w3v.y;
      h = acc2[nt2][nt][2] + b2v.z; s += (h > 0.f ? h : 0.f) * w3v.z;
      h = acc2[nt2][nt][3] + b2v.w; s += (h > 0.f ? h : 0.f) * w3v.w;
    }
    s += __shfl_xor(s, 16, 64);
    s += __shfl_xor(s, 32, 64);
    if (l < 16) {
      const int e = e0w + 16 * nt + l15;
      if (e < E) out[e] = s + b3v;
    }
  }
}

extern "C" void kernel_launch(void* const* d_in, const int* in_sizes, int n_in,
                              void* d_out, int out_size, void* d_ws, size_t ws_size,
                              hipStream_t stream) {
  const float* drug = (const float*)d_in[0];
  const float* dis = (const float*)d_in[1];
  const int* eidx = (const int*)d_in[2];
  const float* W1 = (const float*)d_in[3];
  const float* b1 = (const float*)d_in[4];
  const float* W2 = (const float*)d_in[5];
  const float* b2 = (const float*)d_in[6];
  const float* W3 = (const float*)d_in[7];
  const float* b3 = (const float*)d_in[8];
  float* out = (float*)d_out;

  const int na = in_sizes[0];           // 10000*128
  const int nb = in_sizes[1];           // 5000*128
  const int E = in_sizes[2] / 2;        // 2e6

  unsigned short* ws = (unsigned short*)d_ws;
  unsigned short* drugB = ws;
  unsigned short* disB = ws + na;
  unsigned short* w1f = ws + na + nb;
  unsigned short* w2f = w1f + 128 * 256;
  // total ws use: (na+nb)*2 + 81920 bytes ~= 3.92 MB

  const int tct = (na + nb) >> 3;
  cvt_tables<<<(tct + 255) / 256, 256, 0, stream>>>(drug, dis, drugB, disB, na, nb);
  cvt_weights<<<20, 256, 0, stream>>>(W1, W2, w1f, w2f);

  const int grid = (E + 127) / 128;  // E = 2e6 -> 15625 exact
  mlp_fused<<<grid, 256, 0, stream>>>(drugB, disB, eidx, w1f, w2f, b1, b2, W3, b3, out, E);
}

// Round 16
// 287.071 us; speedup vs baseline: 1.2938x; 1.2938x over previous
//
#include <hip/hip_runtime.h>

// MLP_48687749268221: out[e] = W3 @ relu(W2 @ relu(W1 @ concat(drug[i0],dis[i1]) + b1) + b2) + b3
// E = 2e6, dims 256 -> 128 -> 64 -> 1. bf16 MFMA, f32 accumulate.
// Round 16: R13 (32x32x16 L1 -> L1 LDS B-reads halve vs R11) but with the ONLY
// register profile the compiler has ever held (R6/R11): nf[2][2] 2-deep prefetch
// (16 VGPR), acc 32 VGPR. R13's regression was its 4-deep/8-frag stream being sunk.

typedef __bf16 bf16x8 __attribute__((ext_vector_type(8)));
typedef unsigned short u16x8 __attribute__((ext_vector_type(8)));
typedef float f32x4 __attribute__((ext_vector_type(4)));
typedef float f32x16 __attribute__((ext_vector_type(16)));

static __device__ __forceinline__ unsigned short f2b(float f) {
  // f32 -> bf16 RTNE (inputs finite)
  unsigned int u = __builtin_bit_cast(unsigned int, f);
  u += 0x7FFFu + ((u >> 16) & 1u);
  return (unsigned short)(u >> 16);
}

static __device__ __forceinline__ f32x4 mfma16(u16x8 a, u16x8 b, f32x4 c) {
  return __builtin_amdgcn_mfma_f32_16x16x32_bf16(
      __builtin_bit_cast(bf16x8, a), __builtin_bit_cast(bf16x8, b), c, 0, 0, 0);
}
static __device__ __forceinline__ f32x16 mfma32(u16x8 a, u16x8 b, f32x16 c) {
  return __builtin_amdgcn_mfma_f32_32x32x16_bf16(
      __builtin_bit_cast(bf16x8, a), __builtin_bit_cast(bf16x8, b), c, 0, 0, 0);
}

// ---------- prologue 1: f32 tables -> bf16 tables ----------
__global__ void cvt_tables(const float* __restrict__ a, const float* __restrict__ b,
                           unsigned short* __restrict__ oa, unsigned short* __restrict__ ob,
                           int na, int nb) {
  const int t = blockIdx.x * blockDim.x + threadIdx.x;
  const int ta = na >> 3;
  const float* src;
  unsigned short* dst;
  int i;
  if (t < ta) {
    src = a; dst = oa; i = t;
  } else {
    i = t - ta;
    if (i >= (nb >> 3)) return;
    src = b; dst = ob;
  }
  const float4 f0 = *(const float4*)(src + i * 8);
  const float4 f1 = *(const float4*)(src + i * 8 + 4);
  u16x8 v;
  v[0] = f2b(f0.x); v[1] = f2b(f0.y); v[2] = f2b(f0.z); v[3] = f2b(f0.w);
  v[4] = f2b(f1.x); v[5] = f2b(f1.y); v[6] = f2b(f1.z); v[7] = f2b(f1.w);
  *(u16x8*)(dst + i * 8) = v;
}

// ---------- prologue 2: weights -> bf16 in fragment order (same as R13) ----------
// W1 (32x32x16 A-frag): lane l holds W1[32*ut + (l&31)][16*s + 8*(l>>5) + j], j=0..7.
//   slot t = (ut*16 + s)*64 + l, ut 0..3, s 0..15.
// W2 (16x16x32 A-frag): lane l holds W2[16*nt2 + (l&15)][32*kt + 8*(l>>4) + j].
//   slot u = (nt2*4 + kt)*64 + l, nt2 0..3, kt 0..3.
__global__ void cvt_weights(const float* __restrict__ W1, const float* __restrict__ W2,
                            unsigned short* __restrict__ o1, unsigned short* __restrict__ o2) {
  const int t = blockIdx.x * blockDim.x + threadIdx.x;
  if (t < 4096) {
    const int l = t & 63, s = (t >> 6) & 15, ut = t >> 10;
    const int n = 32 * ut + (l & 31), k0 = 16 * s + 8 * (l >> 5);
    const float* src = W1 + n * 256 + k0;
    u16x8 v;
#pragma unroll
    for (int j = 0; j < 8; ++j) v[j] = f2b(src[j]);
    *(u16x8*)(o1 + t * 8) = v;
  } else if (t < 5120) {
    const int u = t - 4096;
    const int l = u & 63, kt = (u >> 6) & 3, nt = u >> 8;
    const int n = 16 * nt + (l & 15), k0 = 32 * kt + 8 * (l >> 4);
    const float* src = W2 + n * 128 + k0;
    u16x8 v;
#pragma unroll
    for (int j = 0; j < 8; ++j) v[j] = f2b(src[j]);
    *(u16x8*)(o2 + u * 8) = v;
  }
}

// ---------- main fused kernel ----------
// 256 threads = 4 waves. Tile = 64 edges.
// Gather: wave w stages feature-quarter [64w,+64) of all 64 edges (R11, conflict-free).
// L1 (32x32x16): wave (wn2 = w>>1, wm = w&1): units [64wn2,+64) as 2 tiles, edges [32wm,+32).
// L2+L3 (16x16x32): wave wn owns n2-units [16wn,+16), all 64 edges (R11).
// LDS (33792 B -> 4 blocks/CU): A 32 chunks x [64 x 16 B] (chunk = f>>3); H1 16 chunks
// aliased @0 after L1; partials [4][64] f32 @32768.
__global__ __launch_bounds__(256, 4) void mlp_fused(
    const unsigned short* __restrict__ drugB, const unsigned short* __restrict__ disB,
    const int* __restrict__ eidx, const unsigned short* __restrict__ w1frag,
    const unsigned short* __restrict__ w2frag, const float* __restrict__ b1,
    const float* __restrict__ b2, const float* __restrict__ W3,
    const float* __restrict__ b3, float* __restrict__ out, int E) {
  __shared__ __align__(16) unsigned char smem[33792];
  unsigned char* Abase = smem;
  float* partials = (float*)(smem + 32768);

  const int tid = threadIdx.x;
  const int w = tid >> 6;
  const int wn = w;          // L2 unit-quarter (R11 role)
  const int wn2 = w >> 1;    // L1 unit-half
  const int wm = w & 1;      // L1 edge-half
  const int l = tid & 63;
  const int l15 = l & 15;
  const int lq = l >> 4;
  const int hi = l >> 5;     // 0..1
  const int e0 = blockIdx.x * 64;

  // ---- gather: wave w holds feature-quarter [64w,+64) of its lane's edge row ----
  {
    int e = e0 + l;
    if (e >= E) e = E - 1;
    const int idx = eidx[(w >> 1) * E + e];  // w<2: drug, w>=2: dis
    const unsigned short* src = ((w < 2) ? drugB : disB) + (long)idx * 128 + (w & 1) * 64;
    unsigned char* wbase = Abase + w * 8192 + l * 16;
#pragma unroll
    for (int c = 0; c < 8; ++c) {
      const u16x8 v = *(const u16x8*)(src + c * 8);
      *(u16x8*)(wbase + c * 1024) = v;
    }
  }

  // ---- hoisted constants (hidden under gather): W2 frags, b2, W3 ----
  u16x8 w2f[4];
#pragma unroll
  for (int kt = 0; kt < 4; ++kt)
    w2f[kt] = *(const u16x8*)(w2frag + ((wn * 4 + kt) * 64 + l) * 8);
  const float4 b2v = *(const float4*)(b2 + 16 * wn + 4 * lq);
  const float4 w3v = *(const float4*)(W3 + 16 * wn + 4 * lq);
  __syncthreads();

  // ---- layer 1 (32x32x16): D1[unit][edge]; A = W1 frags (2-deep stream), B from LDS ----
  f32x16 acc[2];
#pragma unroll
  for (int i = 0; i < 16; ++i) { acc[0][i] = 0.f; acc[1][i] = 0.f; }

  // B-frag: lane l -> edge 32wm + (l&31), features [16s + 8hi, +8)
  const int boff = hi * 1024 + (32 * wm + (l & 31)) * 16;  // + s*2048
  // W1 frag (ut = 2wn2 + uti, s) at ((ut*16 + s)*64 + l)*8 shorts
  const unsigned short* w1p = w1frag + ((2 * wn2) * 1024 + l) * 8;
  u16x8 nf[2][2];  // [s parity][uti]; s+2 prefetch — the R6/R11-proven 16-VGPR stream
  nf[0][0] = *(const u16x8*)(w1p);
  nf[0][1] = *(const u16x8*)(w1p + 1024 * 8);
  nf[1][0] = *(const u16x8*)(w1p + 64 * 8);
  nf[1][1] = *(const u16x8*)(w1p + (1024 + 64) * 8);
#pragma unroll
  for (int s = 0; s < 16; ++s) {
    const u16x8 c0 = nf[s & 1][0], c1 = nf[s & 1][1];
    if (s < 14) {
      nf[s & 1][0] = *(const u16x8*)(w1p + ((s + 2) * 64) * 8);
      nf[s & 1][1] = *(const u16x8*)(w1p + ((1024 + (s + 2) * 64)) * 8);
    }
    const u16x8 b = *(const u16x8*)(Abase + s * 2048 + boff);
    acc[0] = mfma32(c0, b, acc[0]);
    acc[1] = mfma32(c1, b, acc[1]);
  }
  __syncthreads();  // all waves done reading A before H1 overwrites chunks 0..15

  // ---- H1 epilogue: bias+relu, ushort4 of 4 consecutive units -> chunked H1 ----
  // lane holds D1[32*(2wn2+uti) + (r&3) + 8*(r>>2) + 4hi][32wm + (l&31)], r = 4p+i.
  {
    const int ebyte = (32 * wm + (l & 31)) * 16;
#pragma unroll
    for (int uti = 0; uti < 2; ++uti) {
#pragma unroll
      for (int p = 0; p < 4; ++p) {
        const float4 bv = *(const float4*)(b1 + 32 * (2 * wn2 + uti) + 8 * p + 4 * hi);
        float h0 = acc[uti][4 * p + 0] + bv.x; h0 = h0 > 0.f ? h0 : 0.f;
        float h1 = acc[uti][4 * p + 1] + bv.y; h1 = h1 > 0.f ? h1 : 0.f;
        float h2 = acc[uti][4 * p + 2] + bv.z; h2 = h2 > 0.f ? h2 : 0.f;
        float h3 = acc[uti][4 * p + 3] + bv.w; h3 = h3 > 0.f ? h3 : 0.f;
        ushort4 hv;
        hv.x = f2b(h0); hv.y = f2b(h1); hv.z = f2b(h2); hv.w = f2b(h3);
        *(ushort4*)(Abase + (4 * (2 * wn2 + uti) + p) * 1024 + ebyte + 8 * hi) = hv;
      }
    }
  }
  __syncthreads();

  // ---- layer 2 (16x16x32): D2[n2][edge]; A = W2 frags, B = H1 frags (chunk = 4kt+lq) ----
  const int aoff = lq * 1024 + l15 * 16;
  f32x4 acc2[4];
#pragma unroll
  for (int nt = 0; nt < 4; ++nt) acc2[nt] = (f32x4){0.f, 0.f, 0.f, 0.f};
#pragma unroll
  for (int kt = 0; kt < 4; ++kt) {
#pragma unroll
    for (int nt = 0; nt < 4; ++nt) {
      const u16x8 b = *(const u16x8*)(Abase + kt * 4096 + nt * 256 + aoff);
      acc2[nt] = mfma16(w2f[kt], b, acc2[nt]);
    }
  }

  // ---- layer 3: relu(.+b2) dot W3 (4 units/lane), reduce over lq with 2 shuffles ----
#pragma unroll
  for (int nt = 0; nt < 4; ++nt) {
    float h0 = acc2[nt][0] + b2v.x; h0 = h0 > 0.f ? h0 : 0.f;
    float h1 = acc2[nt][1] + b2v.y; h1 = h1 > 0.f ? h1 : 0.f;
    float h2 = acc2[nt][2] + b2v.z; h2 = h2 > 0.f ? h2 : 0.f;
    float h3 = acc2[nt][3] + b2v.w; h3 = h3 > 0.f ? h3 : 0.f;
    float s = h0 * w3v.x + h1 * w3v.y + h2 * w3v.z + h3 * w3v.w;
    s += __shfl_xor(s, 16, 64);
    s += __shfl_xor(s, 32, 64);
    if (l < 16) partials[wn * 64 + 16 * nt + l15] = s;
  }
  __syncthreads();

  if (tid < 64) {
    const int e = e0 + tid;
    if (e < E) {
      out[e] = partials[tid] + partials[64 + tid] + partials[128 + tid] +
               partials[192 + tid] + b3[0];
    }
  }
}

extern "C" void kernel_launch(void* const* d_in, const int* in_sizes, int n_in,
                              void* d_out, int out_size, void* d_ws, size_t ws_size,
                              hipStream_t stream) {
  const float* drug = (const float*)d_in[0];
  const float* dis = (const float*)d_in[1];
  const int* eidx = (const int*)d_in[2];
  const float* W1 = (const float*)d_in[3];
  const float* b1 = (const float*)d_in[4];
  const float* W2 = (const float*)d_in[5];
  const float* b2 = (const float*)d_in[6];
  const float* W3 = (const float*)d_in[7];
  const float* b3 = (const float*)d_in[8];
  float* out = (float*)d_out;

  const int na = in_sizes[0];           // 10000*128
  const int nb = in_sizes[1];           // 5000*128
  const int E = in_sizes[2] / 2;        // 2e6

  unsigned short* ws = (unsigned short*)d_ws;
  unsigned short* drugB = ws;
  unsigned short* disB = ws + na;
  unsigned short* w1f = ws + na + nb;
  unsigned short* w2f = w1f + 128 * 256;
  // total ws use: (na+nb)*2 + 81920 bytes ~= 3.92 MB

  const int tct = (na + nb) >> 3;
  cvt_tables<<<(tct + 255) / 256, 256, 0, stream>>>(drug, dis, drugB, disB, na, nb);
  cvt_weights<<<20, 256, 0, stream>>>(W1, W2, w1f, w2f);

  const int grid = (E + 63) / 64;
  mlp_fused<<<grid, 256, 0, stream>>>(drugB, disB, eidx, w1f, w2f, b1, b2, W3, b3, out, E);
}

// Round 17
// 223.969 us; speedup vs baseline: 1.6583x; 1.2817x over previous
//
#include <hip/hip_runtime.h>

// MLP_48687749268221: out[e] = W3 @ relu(W2 @ relu(W1 @ concat(drug[i0],dis[i1]) + b1) + b2) + b3
// E = 2e6, dims 256 -> 128 -> 64 -> 1. bf16 MFMA, f32 accumulate.
// Round 17: RESTORE R11 (session best, 224 us) verbatim. 16-round search summary:
//  - chunked linear LDS layout A[chunk][edge][16B] -> bank conflicts 5.2e7 -> 4e6
//  - (4,1) wave split, 2-deep/2-frag W1 stream: the only load schedule the allocator holds
//  - occupancy irrelevant (R12: 84% occ was slower); barrier-free needs >96 VGPR -> spills
//  - 32x32 MFMA, deeper prefetch, launch-bounds tuning: all sunk by allocator (6 rounds)
// Remaining gap to pipe floors is dependent-phase latency — structural at HIP source level.

typedef __bf16 bf16x8 __attribute__((ext_vector_type(8)));
typedef unsigned short u16x8 __attribute__((ext_vector_type(8)));
typedef float f32x4 __attribute__((ext_vector_type(4)));

static __device__ __forceinline__ unsigned short f2b(float f) {
  // f32 -> bf16 RTNE (inputs finite)
  unsigned int u = __builtin_bit_cast(unsigned int, f);
  u += 0x7FFFu + ((u >> 16) & 1u);
  return (unsigned short)(u >> 16);
}

static __device__ __forceinline__ f32x4 mfma_bf16(u16x8 a, u16x8 b, f32x4 c) {
  return __builtin_amdgcn_mfma_f32_16x16x32_bf16(
      __builtin_bit_cast(bf16x8, a), __builtin_bit_cast(bf16x8, b), c, 0, 0, 0);
}

// ---------- prologue 1: f32 tables -> bf16 tables ----------
__global__ void cvt_tables(const float* __restrict__ a, const float* __restrict__ b,
                           unsigned short* __restrict__ oa, unsigned short* __restrict__ ob,
                           int na, int nb) {
  const int t = blockIdx.x * blockDim.x + threadIdx.x;
  const int ta = na >> 3;
  const float* src;
  unsigned short* dst;
  int i;
  if (t < ta) {
    src = a; dst = oa; i = t;
  } else {
    i = t - ta;
    if (i >= (nb >> 3)) return;
    src = b; dst = ob;
  }
  const float4 f0 = *(const float4*)(src + i * 8);
  const float4 f1 = *(const float4*)(src + i * 8 + 4);
  u16x8 v;
  v[0] = f2b(f0.x); v[1] = f2b(f0.y); v[2] = f2b(f0.z); v[3] = f2b(f0.w);
  v[4] = f2b(f1.x); v[5] = f2b(f1.y); v[6] = f2b(f1.z); v[7] = f2b(f1.w);
  *(u16x8*)(dst + i * 8) = v;
}

// ---------- prologue 2: weights -> bf16 in A-fragment order ----------
// Frag (16x16x32): lane l holds elem[dim][k], dim = 16*t + (l&15), k = 32*kt + 8*(l>>4) + j.
// W1 slot t = (ut*8 + kt)*64 + l  (ut 0..7, kt 0..7); W2: (nt2*4 + kt)*64 + l (nt2 0..3, kt 0..3).
__global__ void cvt_weights(const float* __restrict__ W1, const float* __restrict__ W2,
                            unsigned short* __restrict__ o1, unsigned short* __restrict__ o2) {
  const int t = blockIdx.x * blockDim.x + threadIdx.x;
  if (t < 4096) {
    const int l = t & 63, kt = (t >> 6) & 7, ut = t >> 9;
    const int n = 16 * ut + (l & 15), k0 = 32 * kt + 8 * (l >> 4);
    const float* src = W1 + n * 256 + k0;
    u16x8 v;
#pragma unroll
    for (int j = 0; j < 8; ++j) v[j] = f2b(src[j]);
    *(u16x8*)(o1 + t * 8) = v;
  } else if (t < 5120) {
    const int u = t - 4096;
    const int l = u & 63, kt = (u >> 6) & 3, nt = u >> 8;
    const int n = 16 * nt + (l & 15), k0 = 32 * kt + 8 * (l >> 4);
    const float* src = W2 + n * 128 + k0;
    u16x8 v;
#pragma unroll
    for (int j = 0; j < 8; ++j) v[j] = f2b(src[j]);
    *(u16x8*)(o2 + u * 8) = v;
  }
}

// ---------- main fused kernel ----------
// 256 threads = 4 waves; wave wn owns W1 units [32wn,+32) and W2 units [16wn,+16),
// sweeps all 64 edges. LDS (33792 B -> 4 blocks/CU):
//   A: 32 chunks x [64 edges x 16 B] @0 (chunk = kt*4+lq); H1: 16 chunks aliased @0
//   after L1 barrier; partials [4][64] f32 @32768.
__global__ __launch_bounds__(256, 4) void mlp_fused(
    const unsigned short* __restrict__ drugB, const unsigned short* __restrict__ disB,
    const int* __restrict__ eidx, const unsigned short* __restrict__ w1frag,
    const unsigned short* __restrict__ w2frag, const float* __restrict__ b1,
    const float* __restrict__ b2, const float* __restrict__ W3,
    const float* __restrict__ b3, float* __restrict__ out, int E) {
  __shared__ __align__(16) unsigned char smem[33792];
  unsigned char* Abase = smem;
  float* partials = (float*)(smem + 32768);

  const int tid = threadIdx.x;
  const int wn = tid >> 6;   // wave 0..3: unit-column quarter (and gather feature-quarter)
  const int l = tid & 63;
  const int l15 = l & 15;
  const int lq = l >> 4;
  const int e0 = blockIdx.x * 64;

  // per-lane invariant LDS offsets (all linear, no swizzle)
  const int aoff = lq * 1024 + l15 * 16;  // B-frag read: + kt*4096 + nt*256

  // ---- gather: wave wn holds feature-quarter [64wn,+64) of its lane's edge row ----
  // write chunk (8wn + c), byte l*16: 64 lanes contiguous 1 KB -> conflict-free
  {
    int e = e0 + l;
    if (e >= E) e = E - 1;
    const int idx = eidx[(wn >> 1) * E + e];  // wn<2: drug, wn>=2: dis
    const unsigned short* src = ((wn < 2) ? drugB : disB) + (long)idx * 128 + (wn & 1) * 64;
    unsigned char* wbase = Abase + wn * 8192 + l * 16;
#pragma unroll
    for (int c = 0; c < 8; ++c) {
      const u16x8 v = *(const u16x8*)(src + c * 8);
      *(u16x8*)(wbase + c * 1024) = v;
    }
  }

  // ---- W2 A-frags resident (hidden under gather), bias/W3 float4 per lane ----
  u16x8 w2f[4];
#pragma unroll
  for (int kt = 0; kt < 4; ++kt)
    w2f[kt] = *(const u16x8*)(w2frag + ((wn * 4 + kt) * 64 + l) * 8);
  const float4 b1v0 = *(const float4*)(b1 + 32 * wn + 4 * lq);
  const float4 b1v1 = *(const float4*)(b1 + 32 * wn + 16 + 4 * lq);
  const float4 b2v = *(const float4*)(b2 + 16 * wn + 4 * lq);
  const float4 w3v = *(const float4*)(W3 + 16 * wn + 4 * lq);
  __syncthreads();

  // ---- layer 1: D1[unit][edge]; A = W1 frags (2-deep stream), B = edge frags from LDS ----
  f32x4 acc1[2][4];
#pragma unroll
  for (int uti = 0; uti < 2; ++uti)
#pragma unroll
    for (int nt = 0; nt < 4; ++nt) acc1[uti][nt] = (f32x4){0.f, 0.f, 0.f, 0.f};

  const unsigned short* w1p = w1frag + ((2 * wn) * 512 + l) * 8;
  u16x8 nf[2][2];  // [kt parity][uti]; kt+2 prefetch
  nf[0][0] = *(const u16x8*)(w1p);
  nf[0][1] = *(const u16x8*)(w1p + 512 * 8);
  nf[1][0] = *(const u16x8*)(w1p + 64 * 8);
  nf[1][1] = *(const u16x8*)(w1p + (512 + 64) * 8);
#pragma unroll
  for (int kt = 0; kt < 8; ++kt) {
    const u16x8 c0 = nf[kt & 1][0], c1 = nf[kt & 1][1];
    if (kt < 6) {
      nf[kt & 1][0] = *(const u16x8*)(w1p + ((kt + 2) * 64) * 8);
      nf[kt & 1][1] = *(const u16x8*)(w1p + ((512 + (kt + 2) * 64)) * 8);
    }
#pragma unroll
    for (int nt = 0; nt < 4; ++nt) {
      const u16x8 b = *(const u16x8*)(Abase + kt * 4096 + nt * 256 + aoff);
      acc1[0][nt] = mfma_bf16(c0, b, acc1[0][nt]);
      acc1[1][nt] = mfma_bf16(c1, b, acc1[1][nt]);
    }
  }
  __syncthreads();  // all waves done reading A before H1 overwrites chunks 0..15

  // ---- H1 epilogue: bias+relu, pack 4 bf16 -> 8B write, chunked layout ----
  // lane holds D1[u0..u0+4)[e], u0 = 32wn+16uti+4lq, e = 16nt+l15.
  // H1 chunk = wn*4 + 2uti + (lq>>1); byte-in-slot (lq&1)*8.
  {
    unsigned char* hw = Abase + wn * 4096 + (lq >> 1) * 1024 + (lq & 1) * 8 + l15 * 16;
#pragma unroll
    for (int uti = 0; uti < 2; ++uti) {
      const float4 bv = uti ? b1v1 : b1v0;
#pragma unroll
      for (int nt = 0; nt < 4; ++nt) {
        float h0 = acc1[uti][nt][0] + bv.x; h0 = h0 > 0.f ? h0 : 0.f;
        float h1 = acc1[uti][nt][1] + bv.y; h1 = h1 > 0.f ? h1 : 0.f;
        float h2 = acc1[uti][nt][2] + bv.z; h2 = h2 > 0.f ? h2 : 0.f;
        float h3 = acc1[uti][nt][3] + bv.w; h3 = h3 > 0.f ? h3 : 0.f;
        ushort4 hv;
        hv.x = f2b(h0); hv.y = f2b(h1); hv.z = f2b(h2); hv.w = f2b(h3);
        *(ushort4*)(hw + uti * 2048 + nt * 256) = hv;
      }
    }
  }
  __syncthreads();

  // ---- layer 2: D2[n2][edge]; A = W2 frags (resident), B = H1 frags from LDS ----
  f32x4 acc2[4];
#pragma unroll
  for (int nt = 0; nt < 4; ++nt) acc2[nt] = (f32x4){0.f, 0.f, 0.f, 0.f};
#pragma unroll
  for (int kt = 0; kt < 4; ++kt) {
#pragma unroll
    for (int nt = 0; nt < 4; ++nt) {
      const u16x8 b = *(const u16x8*)(Abase + kt * 4096 + nt * 256 + aoff);
      acc2[nt] = mfma_bf16(w2f[kt], b, acc2[nt]);
    }
  }

  // ---- layer 3: relu(.+b2) dot W3 (4 units per lane), reduce over lq with 2 shuffles ----
#pragma unroll
  for (int nt = 0; nt < 4; ++nt) {
    float h0 = acc2[nt][0] + b2v.x; h0 = h0 > 0.f ? h0 : 0.f;
    float h1 = acc2[nt][1] + b2v.y; h1 = h1 > 0.f ? h1 : 0.f;
    float h2 = acc2[nt][2] + b2v.z; h2 = h2 > 0.f ? h2 : 0.f;
    float h3 = acc2[nt][3] + b2v.w; h3 = h3 > 0.f ? h3 : 0.f;
    float s = h0 * w3v.x + h1 * w3v.y + h2 * w3v.z + h3 * w3v.w;
    s += __shfl_xor(s, 16, 64);
    s += __shfl_xor(s, 32, 64);
    if (l < 16) partials[wn * 64 + 16 * nt + l15] = s;
  }
  __syncthreads();

  if (tid < 64) {
    const int e = e0 + tid;
    if (e < E) {
      out[e] = partials[tid] + partials[64 + tid] + partials[128 + tid] +
               partials[192 + tid] + b3[0];
    }
  }
}

extern "C" void kernel_launch(void* const* d_in, const int* in_sizes, int n_in,
                              void* d_out, int out_size, void* d_ws, size_t ws_size,
                              hipStream_t stream) {
  const float* drug = (const float*)d_in[0];
  const float* dis = (const float*)d_in[1];
  const int* eidx = (const int*)d_in[2];
  const float* W1 = (const float*)d_in[3];
  const float* b1 = (const float*)d_in[4];
  const float* W2 = (const float*)d_in[5];
  const float* b2 = (const float*)d_in[6];
  const float* W3 = (const float*)d_in[7];
  const float* b3 = (const float*)d_in[8];
  float* out = (float*)d_out;

  const int na = in_sizes[0];           // 10000*128
  const int nb = in_sizes[1];           // 5000*128
  const int E = in_sizes[2] / 2;        // 2e6

  unsigned short* ws = (unsigned short*)d_ws;
  unsigned short* drugB = ws;
  unsigned short* disB = ws + na;
  unsigned short* w1f = ws + na + nb;
  unsigned short* w2f = w1f + 128 * 256;
  // total ws use: (na+nb)*2 + 81920 bytes ~= 3.92 MB

  const int tct = (na + nb) >> 3;
  cvt_tables<<<(tct + 255) / 256, 256, 0, stream>>>(drug, dis, drugB, disB, na, nb);
  cvt_weights<<<20, 256, 0, stream>>>(W1, W2, w1f, w2f);

  const int grid = (E + 63) / 64;
  mlp_fused<<<grid, 256, 0, stream>>>(drugB, disB, eidx, w1f, w2f, b1, b2, W3, b3, out, E);
}